// Round 6
// baseline (328.393 us; speedup 1.0000x reference)
//
#include <hip/hip_runtime.h>

#define T_TOK 16384
#define DM 1024
#define DFF 4096
#define NE 8
#define CAP 320
#define RP 384   // per-expert padded rows (3 x 128 tiles)

typedef __attribute__((ext_vector_type(8))) short bf16x8;
typedef __attribute__((ext_vector_type(4))) float f32x4;

__device__ __forceinline__ unsigned short f2bf(float f) {
    unsigned int u = __builtin_bit_cast(unsigned int, f);
    u += 0x7FFFu + ((u >> 16) & 1u);   // RNE (finite inputs)
    return (unsigned short)(u >> 16);
}

__device__ __forceinline__ void gload_lds16(const void* g, void* l) {
    __builtin_amdgcn_global_load_lds(
        (const __attribute__((address_space(1))) unsigned int*)g,
        (__attribute__((address_space(3))) unsigned int*)l,
        16, 0, 0);
}

// ---------------- zero out ----------------
__global__ __launch_bounds__(256) void k_zero_out(float4* __restrict__ p, int n4) {
    for (int i = blockIdx.x * 256 + threadIdx.x; i < n4; i += gridDim.x * 256)
        p[i] = make_float4(0.f, 0.f, 0.f, 0.f);
}

// ---------------- init ----------------
__global__ void k_init(float* sumprob) {
    if (threadIdx.x < NE) sumprob[threadIdx.x] = 0.f;
}

// ---------------- router: 4 threads per token ----------------
__global__ __launch_bounds__(256) void k_router(
    const float* __restrict__ x, const float* __restrict__ rw,
    const float* __restrict__ rb, int* __restrict__ eidx,
    float* __restrict__ sumprob)
{
    __shared__ float w[DM * NE];
    for (int i = threadIdx.x; i < DM * NE; i += 256) w[i] = rw[i];
    __syncthreads();

    const int tid = threadIdx.x;
    const int t = blockIdx.x * 64 + (tid >> 2);
    const int part = tid & 3;
    const float4* xr = reinterpret_cast<const float4*>(x + (size_t)t * DM + part * 256);

    float a[NE] = {};
    for (int kk = 0; kk < 64; ++kk) {
        float4 xv = xr[kk];
        int base = part * 256 + kk * 4;
        #pragma unroll
        for (int c = 0; c < 4; ++c) {
            float xs = (c == 0) ? xv.x : (c == 1) ? xv.y : (c == 2) ? xv.z : xv.w;
            const float4* wr = reinterpret_cast<const float4*>(&w[(base + c) * NE]);
            float4 w0 = wr[0], w1 = wr[1];
            a[0] += xs * w0.x; a[1] += xs * w0.y; a[2] += xs * w0.z; a[3] += xs * w0.w;
            a[4] += xs * w1.x; a[5] += xs * w1.y; a[6] += xs * w1.z; a[7] += xs * w1.w;
        }
    }
    #pragma unroll
    for (int e = 0; e < NE; ++e) {
        a[e] += __shfl_xor(a[e], 1);
        a[e] += __shfl_xor(a[e], 2);
        a[e] += rb[e];
    }

    float m = a[0]; int bi = 0;
    #pragma unroll
    for (int e = 1; e < NE; ++e) if (a[e] > m) { m = a[e]; bi = e; }
    float p[NE], s = 0.f;
    #pragma unroll
    for (int e = 0; e < NE; ++e) { p[e] = __expf(a[e] - m); s += p[e]; }
    float inv = 1.f / s;
    if (part == 0) eidx[t] = bi;

    #pragma unroll
    for (int e = 0; e < NE; ++e) {
        float v = (part == 0) ? p[e] * inv : 0.f;
        #pragma unroll
        for (int o = 32; o > 0; o >>= 1) v += __shfl_down(v, o);
        if ((tid & 63) == 0) atomicAdd(&sumprob[e], v);
    }
}

// ---------------- per-expert sequential rank scan (1024 threads) ----------------
__global__ __launch_bounds__(1024) void k_scan(
    const int* __restrict__ eidx, int* __restrict__ s2t, int* __restrict__ counts)
{
    const int e = blockIdx.x;
    const int tid = threadIdx.x, lane = tid & 63, w = tid >> 6;
    __shared__ int wts[16];

    for (int i = tid; i < CAP; i += 1024) s2t[e * CAP + i] = -1;
    __syncthreads();

    int running = 0;
    for (int base = 0; base < T_TOK; base += 1024) {
        int t = base + tid;
        bool flag = (eidx[t] == e);
        unsigned long long mask = __ballot(flag);
        int wp = __popcll(mask & ((1ull << lane) - 1ull));
        if (lane == 0) wts[w] = __popcll(mask);
        __syncthreads();
        int woff = 0, btot = 0;
        #pragma unroll
        for (int j = 0; j < 16; ++j) { int v = wts[j]; btot += v; if (j < w) woff += v; }
        if (flag) {
            int rank = running + woff + wp;
            if (rank < CAP) s2t[e * CAP + rank] = t;
        }
        running += btot;
        __syncthreads();
    }
    if (tid == 0) counts[e] = running;
}

// ---------------- load-balance loss ----------------
__global__ void k_lb(const int* __restrict__ counts, const float* __restrict__ sumprob,
                     float* __restrict__ out_lb)
{
    if (threadIdx.x == 0) {
        float acc = 0.f;
        for (int e = 0; e < NE; ++e) acc += (float)counts[e] * sumprob[e];
        *out_lb = (float)NE * acc / ((float)T_TOK * (float)T_TOK);
    }
}

// ---------------- gather kept tokens -> bf16 (zero padding rows) ----------------
__global__ __launch_bounds__(256) void k_gather(
    const float* __restrict__ x, const int* __restrict__ s2t,
    unsigned short* __restrict__ xb)
{
    int r = blockIdx.x;
    int e = r / RP, i = r - e * RP;
    int tok = (i < CAP) ? s2t[e * CAP + i] : -1;
    int tid = threadIdx.x;
    unsigned short* dst = xb + (size_t)r * DM + tid * 4;
    if (tok >= 0) {
        float4 v = reinterpret_cast<const float4*>(x + (size_t)tok * DM)[tid];
        short4 b = make_short4((short)f2bf(v.x), (short)f2bf(v.y),
                               (short)f2bf(v.z), (short)f2bf(v.w));
        *reinterpret_cast<short4*>(dst) = b;
    } else {
        *reinterpret_cast<short4*>(dst) = make_short4(0, 0, 0, 0);
    }
}

// ---------------- transpose+cvt: src f32 [NE][R][C] -> dst bf16 [NE][chrows][R] ----
// dst[e][c - cbase][r] = src[e][r][c], for c in [cbase, cbase + chrows)
template<int R, int C>
__global__ __launch_bounds__(256) void k_cvt_t(
    const float* __restrict__ src, unsigned short* __restrict__ dst,
    int cbase, int chrows)
{
    __shared__ float t[64][65];
    const int e = blockIdx.z;
    const int r0 = blockIdx.y * 64;
    const int c0g = cbase + blockIdx.x * 64;   // global col base
    const int tid = threadIdx.x;

    const float* S = src + ((size_t)e * R + r0) * C + c0g;
    int row = tid >> 2, q = tid & 3;
    #pragma unroll
    for (int i = 0; i < 4; ++i) {
        int f = q + i * 4;                      // float4 index within row
        float4 v = *reinterpret_cast<const float4*>(S + (size_t)row * C + f * 4);
        t[row][f * 4 + 0] = v.x; t[row][f * 4 + 1] = v.y;
        t[row][f * 4 + 2] = v.z; t[row][f * 4 + 3] = v.w;
    }
    __syncthreads();

    int orr = tid >> 3, mb = (tid & 7) * 8;
    #pragma unroll
    for (int p = 0; p < 2; ++p) {
        int oc = orr + p * 32;                  // orig col within tile = out row
        bf16x8 v;
        #pragma unroll
        for (int j = 0; j < 8; ++j) v[j] = (short)f2bf(t[mb + j][oc]);
        *reinterpret_cast<bf16x8*>(
            dst + ((size_t)e * chrows + (c0g - cbase) + oc) * R + r0 + mb) = v;
    }
}

// ---------------- grouped GEMM (m97 structure): C[e] = act(A[e] @ Bt[e]^T + bias) --
// A: bf16 [NE][RP][RS] row-major (k-contig). Bt: bf16 [NE][chn][RS] (n-major,
// k-contig). Both staged via global_load_lds (dwordx4) into lA/lB[2][128][4];
// fragment ds_read_b128 covers a contiguous 1KB region per wave -> conflict-free.
// One vmcnt(0)+barrier per K-step (m97 scheme; multi-block TLP hides the drain).
// MFMA 16x16x32 bf16: A-frag row=lane&15, k=8*(lane>>4)+j; C/D col=lane&15,
// row=4*(lane>>4)+i.
// TOOUT: scatter rows via s2t with 2-way split-K atomicAdd (order-independent).
template<int NK, int RS, int NFULL, bool RELU, bool TOOUT, typename OutT>
__global__ __launch_bounds__(256, 4) void k_gemm(
    const unsigned short* __restrict__ A, const unsigned short* __restrict__ Bt,
    const float* __restrict__ bias, OutT* __restrict__ C,
    const int* __restrict__ s2t, int ntl, int chn, int n_add)
{
    __shared__ bf16x8 lA[2][128][4];
    __shared__ bf16x8 lB[2][128][4];

    const int gx = blockIdx.x;
    const int e  = blockIdx.z;
    const int m0 = blockIdx.y * 128;
    const int n0 = (gx % ntl) * 128;
    const int kb0 = (gx / ntl) * (NK * 32);
    const int tid = threadIdx.x, lane = tid & 63;
    const int w = tid >> 6, wm = w >> 1, wn = w & 1;
    const int lrow = lane & 15, kg = lane >> 4;

    const unsigned short* Ae = A + ((size_t)e * RP + m0) * RS + kb0;
    const unsigned short* Be = Bt + ((size_t)e * chn + n0) * RS + kb0;

    float bv[4];
    #pragma unroll
    for (int n = 0; n < 4; ++n)
        bv[n] = (kb0 == 0) ? bias[e * NFULL + n_add + n0 + wn * 64 + n * 16 + lrow] : 0.f;

    auto stage = [&](const unsigned short* gb, bf16x8* ld, int ks) {
        #pragma unroll
        for (int c = 0; c < 2; ++c) {
            int bofs = c * 256 + w * 64;        // wave-uniform chunk base
            int idx = bofs + lane;
            gload_lds16(gb + (size_t)(idx >> 2) * RS + ks * 32 + (idx & 3) * 8,
                        ld + bofs);
        }
    };

    f32x4 acc[4][4] = {};

    stage(Ae, &lA[0][0][0], 0);
    stage(Be, &lB[0][0][0], 0);
    asm volatile("s_waitcnt vmcnt(0)" ::: "memory");
    __builtin_amdgcn_s_barrier();

    for (int ks = 0; ks < NK; ++ks) {
        const int buf = ks & 1;
        if (ks + 1 < NK) {
            stage(Ae, &lA[buf ^ 1][0][0], ks + 1);
            stage(Be, &lB[buf ^ 1][0][0], ks + 1);
        }
        bf16x8 af[4], bfr[4];
        #pragma unroll
        for (int m = 0; m < 4; ++m) af[m] = lA[buf][wm * 64 + m * 16 + lrow][kg];
        #pragma unroll
        for (int n = 0; n < 4; ++n) bfr[n] = lB[buf][wn * 64 + n * 16 + lrow][kg];
        #pragma unroll
        for (int m = 0; m < 4; ++m)
            #pragma unroll
            for (int n = 0; n < 4; ++n)
                acc[m][n] = __builtin_amdgcn_mfma_f32_16x16x32_bf16(
                    af[m], bfr[n], acc[m][n], 0, 0, 0);
        asm volatile("s_waitcnt vmcnt(0) lgkmcnt(0)" ::: "memory");
        __builtin_amdgcn_s_barrier();
    }

    if constexpr (TOOUT) {
        #pragma unroll
        for (int m = 0; m < 4; ++m) {
            #pragma unroll
            for (int i = 0; i < 4; ++i) {
                int row = m0 + wm * 64 + m * 16 + kg * 4 + i;
                if (row < CAP) {
                    int tok = s2t[e * CAP + row];
                    if (tok >= 0) {
                        #pragma unroll
                        for (int n = 0; n < 4; ++n) {
                            int col = n_add + n0 + wn * 64 + n * 16 + lrow;
                            atomicAdd((float*)C + (size_t)tok * NFULL + col,
                                      acc[m][n][i] + bv[n]);
                        }
                    }
                }
            }
        }
    } else {
        #pragma unroll
        for (int n = 0; n < 4; ++n) {
            int col = n_add + n0 + wn * 64 + n * 16 + lrow;
            #pragma unroll
            for (int m = 0; m < 4; ++m) {
                int rbase = m0 + wm * 64 + m * 16 + kg * 4;
                #pragma unroll
                for (int i = 0; i < 4; ++i) {
                    float v = acc[m][n][i] + bv[n];
                    if (RELU) v = fmaxf(v, 0.f);
                    ((unsigned short*)C)[((size_t)e * RP + rbase + i) * NFULL + col] = f2bf(v);
                }
            }
        }
    }
}

extern "C" void kernel_launch(void* const* d_in, const int* in_sizes, int n_in,
                              void* d_out, int out_size, void* d_ws, size_t ws_size,
                              hipStream_t stream)
{
    const float* x  = (const float*)d_in[0];
    const float* rw = (const float*)d_in[1];
    const float* rb = (const float*)d_in[2];
    const float* w1 = (const float*)d_in[3];
    const float* b1 = (const float*)d_in[4];
    const float* w2 = (const float*)d_in[5];
    const float* b2 = (const float*)d_in[6];
    float* out = (float*)d_out;

    char* ws = (char*)d_ws;
    int*   eidx    = (int*)(ws);                         // 16384 int
    int*   s2t     = (int*)(ws + 65536);                 // 2560 int
    int*   counts  = (int*)(ws + 75776);                 // 8 int
    float* sumprob = (float*)(ws + 75840);               // 8 f32
    unsigned short* xb = (unsigned short*)(ws + 98304);              // [NE][RP][DM] bf16, 6.29 MB
    unsigned short* h  = (unsigned short*)(ws + 98304 + 6291456);    // [NE][RP][DFF] bf16, 25.2 MB
    unsigned short* W  = (unsigned short*)(ws + 98304 + 6291456 + 25165824); // weight region

    // chunk count so that one bf16 weight chunk fits in the remaining scratch
    size_t wbase = 98304 + 6291456 + 25165824;
    size_t avail = (ws_size > wbase) ? ws_size - wbase : 0;
    int NCH = 1;
    while (NCH < 8 && ((size_t)NE * DFF * DM * 2) / NCH > avail) NCH <<= 1;

    hipLaunchKernelGGL(k_zero_out, dim3(1024), dim3(256), 0, stream,
                       (float4*)out, T_TOK * DM / 4);
    hipLaunchKernelGGL(k_init, dim3(1), dim3(64), 0, stream, sumprob);
    hipLaunchKernelGGL(k_router, dim3(T_TOK / 64), dim3(256), 0, stream,
                       x, rw, rb, eidx, sumprob);
    hipLaunchKernelGGL(k_scan, dim3(NE), dim3(1024), 0, stream, eidx, s2t, counts);
    hipLaunchKernelGGL(k_lb, dim3(1), dim3(64), 0, stream,
                       counts, sumprob, out + (size_t)T_TOK * DM);
    hipLaunchKernelGGL(k_gather, dim3(NE * RP), dim3(256), 0, stream, x, s2t, xb);

    // GEMM1: h = relu(xb @ w1 + b1); w1t chunks: bf16 [NE][chn1][DM]
    int chn1 = DFF / NCH;
    for (int c = 0; c < NCH; ++c) {
        hipLaunchKernelGGL((k_cvt_t<DM, DFF>), dim3(chn1 / 64, DM / 64, NE),
                           dim3(256), 0, stream, w1, W, c * chn1, chn1);
        hipLaunchKernelGGL((k_gemm<32, DM, DFF, true, false, unsigned short>),
                           dim3(chn1 / 128, RP / 128, NE), dim3(256), 0, stream,
                           xb, W, b1, h, (const int*)nullptr, chn1 / 128, chn1, c * chn1);
    }

    // GEMM2: out[tok] += h @ w2 + b2 (split-K=2 atomics); w2t chunks: bf16 [NE][chn2][DFF]
    int chn2 = DM / NCH;
    for (int c = 0; c < NCH; ++c) {
        hipLaunchKernelGGL((k_cvt_t<DFF, DM>), dim3(chn2 / 64, DFF / 64, NE),
                           dim3(256), 0, stream, w2, W, c * chn2, chn2);
        hipLaunchKernelGGL((k_gemm<64, DFF, DM, false, true, float>),
                           dim3((chn2 / 128) * 2, RP / 128, NE), dim3(256), 0, stream,
                           h, W, b2, out, s2t, chn2 / 128, chn2, c * chn2);
    }
}

// Round 7
// 248.102 us; speedup vs baseline: 1.3236x; 1.3236x over previous
//
#include <hip/hip_runtime.h>

#define T_TOK 16384
#define DM 1024
#define DFF 4096
#define NE 8
#define CAP 320
#define RP 384     // per-expert padded rows (3 x 128 tiles)
#define RSPLIT 8
#define KSP (DM / RSPLIT)   // 128

typedef __attribute__((ext_vector_type(8))) short bf16x8;
typedef __attribute__((ext_vector_type(4))) float f32x4;

__device__ __forceinline__ unsigned short f2bf(float f) {
    unsigned int u = __builtin_bit_cast(unsigned int, f);
    u += 0x7FFFu + ((u >> 16) & 1u);   // RNE (finite inputs)
    return (unsigned short)(u >> 16);
}

__device__ __forceinline__ void gload_lds16(const void* g, void* l) {
    __builtin_amdgcn_global_load_lds(
        (const __attribute__((address_space(1))) unsigned int*)g,
        (__attribute__((address_space(3))) unsigned int*)l,
        16, 0, 0);
}

// ---------------- zero out ----------------
__global__ __launch_bounds__(256) void k_zero_out(float4* __restrict__ p, int n4) {
    for (int i = blockIdx.x * 256 + threadIdx.x; i < n4; i += gridDim.x * 256)
        p[i] = make_float4(0.f, 0.f, 0.f, 0.f);
}

// ---------------- init ----------------
__global__ void k_init(float* sumprob) {
    if (threadIdx.x < NE) sumprob[threadIdx.x] = 0.f;
}

// ---------------- router pass 1: partial logits, K split 8 ways ----------------
// part[s][t][e] = sum_{k in slice s} x[t][k] * rw[k][e]
__global__ __launch_bounds__(256) void k_logits(
    const float* __restrict__ x, const float* __restrict__ rw,
    float* __restrict__ part)
{
    __shared__ float ws_[KSP][NE];    // 4 KB, w slice
    __shared__ float xs[256][17];     // 17.4 KB (17 coprime 32 -> conflict-free)
    const int s = blockIdx.y, t0 = blockIdx.x * 256, tid = threadIdx.x;

    ((float4*)&ws_[0][0])[tid] = ((const float4*)(rw + s * KSP * NE))[tid];

    float a[NE] = {};
    for (int c = 0; c < KSP / 16; ++c) {
        __syncthreads();
        #pragma unroll
        for (int j = 0; j < 4; ++j) {
            int idx = tid + j * 256;
            int row = idx >> 2, f = idx & 3;
            float4 v = *(const float4*)(x + (size_t)(t0 + row) * DM + s * KSP + c * 16 + f * 4);
            xs[row][f * 4 + 0] = v.x; xs[row][f * 4 + 1] = v.y;
            xs[row][f * 4 + 2] = v.z; xs[row][f * 4 + 3] = v.w;
        }
        __syncthreads();
        #pragma unroll
        for (int k = 0; k < 16; ++k) {
            float xv = xs[tid][k];
            const float* wr = &ws_[c * 16 + k][0];   // wave-uniform -> broadcast
            #pragma unroll
            for (int e = 0; e < NE; ++e) a[e] += xv * wr[e];
        }
    }
    float4* dst = (float4*)(part + ((size_t)s * T_TOK + t0 + tid) * NE);
    dst[0] = make_float4(a[0], a[1], a[2], a[3]);
    dst[1] = make_float4(a[4], a[5], a[6], a[7]);
}

// ---------------- router pass 2: reduce, softmax, argmax, prob sums ----------------
__global__ __launch_bounds__(256) void k_reduce(
    const float* __restrict__ part, const float* __restrict__ rb,
    int* __restrict__ eidx, float* __restrict__ sumprob)
{
    int t = blockIdx.x * 256 + threadIdx.x;
    float a[NE];
    #pragma unroll
    for (int e = 0; e < NE; ++e) a[e] = rb[e];
    for (int s = 0; s < RSPLIT; ++s) {        // fixed order -> deterministic
        const float4* p = (const float4*)(part + ((size_t)s * T_TOK + t) * NE);
        float4 v0 = p[0], v1 = p[1];
        a[0] += v0.x; a[1] += v0.y; a[2] += v0.z; a[3] += v0.w;
        a[4] += v1.x; a[5] += v1.y; a[6] += v1.z; a[7] += v1.w;
    }
    float m = a[0]; int bi = 0;
    #pragma unroll
    for (int e = 1; e < NE; ++e) if (a[e] > m) { m = a[e]; bi = e; }
    float p[NE], s = 0.f;
    #pragma unroll
    for (int e = 0; e < NE; ++e) { p[e] = __expf(a[e] - m); s += p[e]; }
    float inv = 1.f / s;
    eidx[t] = bi;
    #pragma unroll
    for (int e = 0; e < NE; ++e) {
        float v = p[e] * inv;
        #pragma unroll
        for (int o = 32; o > 0; o >>= 1) v += __shfl_down(v, o);
        if ((threadIdx.x & 63) == 0) atomicAdd(&sumprob[e], v);
    }
}

// ---------------- per-expert sequential rank scan (1024 threads) ----------------
__global__ __launch_bounds__(1024) void k_scan(
    const int* __restrict__ eidx, int* __restrict__ s2t, int* __restrict__ counts)
{
    const int e = blockIdx.x;
    const int tid = threadIdx.x, lane = tid & 63, w = tid >> 6;
    __shared__ int wts[16];

    for (int i = tid; i < CAP; i += 1024) s2t[e * CAP + i] = -1;
    __syncthreads();

    int running = 0;
    for (int base = 0; base < T_TOK; base += 1024) {
        int t = base + tid;
        bool flag = (eidx[t] == e);
        unsigned long long mask = __ballot(flag);
        int wp = __popcll(mask & ((1ull << lane) - 1ull));
        if (lane == 0) wts[w] = __popcll(mask);
        __syncthreads();
        int woff = 0, btot = 0;
        #pragma unroll
        for (int j = 0; j < 16; ++j) { int v = wts[j]; btot += v; if (j < w) woff += v; }
        if (flag) {
            int rank = running + woff + wp;
            if (rank < CAP) s2t[e * CAP + rank] = t;
        }
        running += btot;
        __syncthreads();
    }
    if (tid == 0) counts[e] = running;
}

// ---------------- load-balance loss ----------------
__global__ void k_lb(const int* __restrict__ counts, const float* __restrict__ sumprob,
                     float* __restrict__ out_lb)
{
    if (threadIdx.x == 0) {
        float acc = 0.f;
        for (int e = 0; e < NE; ++e) acc += (float)counts[e] * sumprob[e];
        *out_lb = (float)NE * acc / ((float)T_TOK * (float)T_TOK);
    }
}

// ---------------- gather kept tokens -> bf16 (zero padding rows) ----------------
__global__ __launch_bounds__(256) void k_gather(
    const float* __restrict__ x, const int* __restrict__ s2t,
    unsigned short* __restrict__ xb)
{
    int r = blockIdx.x;
    int e = r / RP, i = r - e * RP;
    int tok = (i < CAP) ? s2t[e * CAP + i] : -1;
    int tid = threadIdx.x;
    unsigned short* dst = xb + (size_t)r * DM + tid * 4;
    if (tok >= 0) {
        float4 v = reinterpret_cast<const float4*>(x + (size_t)tok * DM)[tid];
        short4 b = make_short4((short)f2bf(v.x), (short)f2bf(v.y),
                               (short)f2bf(v.z), (short)f2bf(v.w));
        *reinterpret_cast<short4*>(dst) = b;
    } else {
        *reinterpret_cast<short4*>(dst) = make_short4(0, 0, 0, 0);
    }
}

// ---------------- transpose+cvt: src f32 [NE][R][C] -> dst bf16 [NE][chrows][R] ----
template<int R, int C>
__global__ __launch_bounds__(256) void k_cvt_t(
    const float* __restrict__ src, unsigned short* __restrict__ dst,
    int cbase, int chrows)
{
    __shared__ float t[64][65];
    const int e = blockIdx.z;
    const int r0 = blockIdx.y * 64;
    const int c0g = cbase + blockIdx.x * 64;
    const int tid = threadIdx.x;

    const float* S = src + ((size_t)e * R + r0) * C + c0g;
    int row = tid >> 2, q = tid & 3;
    #pragma unroll
    for (int i = 0; i < 4; ++i) {
        int f = q + i * 4;
        float4 v = *reinterpret_cast<const float4*>(S + (size_t)row * C + f * 4);
        t[row][f * 4 + 0] = v.x; t[row][f * 4 + 1] = v.y;
        t[row][f * 4 + 2] = v.z; t[row][f * 4 + 3] = v.w;
    }
    __syncthreads();

    int orr = tid >> 3, mb = (tid & 7) * 8;
    #pragma unroll
    for (int p = 0; p < 2; ++p) {
        int oc = orr + p * 32;
        bf16x8 v;
        #pragma unroll
        for (int j = 0; j < 8; ++j) v[j] = (short)f2bf(t[mb + j][oc]);
        *reinterpret_cast<bf16x8*>(
            dst + ((size_t)e * chrows + (c0g - cbase) + oc) * R + r0 + mb) = v;
    }
}

// ---------------- grouped GEMM (m97 structure + XCD-chunked swizzle) -------------
// Flattened 1D grid, decode: e = j&7 (XCD-chunk = expert, assuming round-robin
// j%8 -> XCD), then m fastest within trio (shares B panel), n next, split outer.
// A: bf16 [NE][RP][RS] k-contig; Bt: bf16 [NE][chn][RS] n-major k-contig.
// Both staged via global_load_lds into lA/lB[2][128][4]; fragment ds_read_b128
// is a contiguous 1KB region per wave -> conflict-free.
// MFMA 16x16x32 bf16: A-frag row=lane&15, k=8*(lane>>4)+j; C/D col=lane&15,
// row=4*(lane>>4)+i.
// TOOUT: scatter rows via s2t with 2-way split-K atomicAdd (order-independent).
template<int NK, int RS, int NFULL, bool RELU, bool TOOUT, typename OutT>
__global__ __launch_bounds__(256, 4) void k_gemm(
    const unsigned short* __restrict__ A, const unsigned short* __restrict__ Bt,
    const float* __restrict__ bias, OutT* __restrict__ C,
    const int* __restrict__ s2t, int ntl, int chn, int n_add)
{
    __shared__ bf16x8 lA[2][128][4];
    __shared__ bf16x8 lB[2][128][4];

    const int j = blockIdx.x;
    const int e = j & 7;
    const int s = j >> 3;
    const int split = s / (ntl * 3);
    const int r2 = s % (ntl * 3);
    const int nt = r2 / 3, mt = r2 % 3;

    const int m0 = mt * 128;
    const int n0 = nt * 128;
    const int kb0 = split * (NK * 32);
    const int tid = threadIdx.x, lane = tid & 63;
    const int w = tid >> 6, wm = w >> 1, wn = w & 1;
    const int lrow = lane & 15, kg = lane >> 4;

    const unsigned short* Ae = A + ((size_t)e * RP + m0) * RS + kb0;
    const unsigned short* Be = Bt + ((size_t)e * chn + n0) * RS + kb0;

    float bv[4];
    #pragma unroll
    for (int n = 0; n < 4; ++n)
        bv[n] = (kb0 == 0) ? bias[e * NFULL + n_add + n0 + wn * 64 + n * 16 + lrow] : 0.f;

    auto stage = [&](const unsigned short* gb, bf16x8* ld, int ks) {
        #pragma unroll
        for (int c = 0; c < 2; ++c) {
            int bofs = c * 256 + w * 64;
            int idx = bofs + lane;
            gload_lds16(gb + (size_t)(idx >> 2) * RS + ks * 32 + (idx & 3) * 8,
                        ld + bofs);
        }
    };

    f32x4 acc[4][4] = {};

    stage(Ae, &lA[0][0][0], 0);
    stage(Be, &lB[0][0][0], 0);
    asm volatile("s_waitcnt vmcnt(0)" ::: "memory");
    __builtin_amdgcn_s_barrier();

    for (int ks = 0; ks < NK; ++ks) {
        const int buf = ks & 1;
        if (ks + 1 < NK) {
            stage(Ae, &lA[buf ^ 1][0][0], ks + 1);
            stage(Be, &lB[buf ^ 1][0][0], ks + 1);
        }
        bf16x8 af[4], bfr[4];
        #pragma unroll
        for (int m = 0; m < 4; ++m) af[m] = lA[buf][wm * 64 + m * 16 + lrow][kg];
        #pragma unroll
        for (int n = 0; n < 4; ++n) bfr[n] = lB[buf][wn * 64 + n * 16 + lrow][kg];
        #pragma unroll
        for (int m = 0; m < 4; ++m)
            #pragma unroll
            for (int n = 0; n < 4; ++n)
                acc[m][n] = __builtin_amdgcn_mfma_f32_16x16x32_bf16(
                    af[m], bfr[n], acc[m][n], 0, 0, 0);
        asm volatile("s_waitcnt vmcnt(0) lgkmcnt(0)" ::: "memory");
        __builtin_amdgcn_s_barrier();
    }

    if constexpr (TOOUT) {
        #pragma unroll
        for (int m = 0; m < 4; ++m) {
            #pragma unroll
            for (int i = 0; i < 4; ++i) {
                int row = m0 + wm * 64 + m * 16 + kg * 4 + i;
                if (row < CAP) {
                    int tok = s2t[e * CAP + row];
                    if (tok >= 0) {
                        #pragma unroll
                        for (int n = 0; n < 4; ++n) {
                            int col = n_add + n0 + wn * 64 + n * 16 + lrow;
                            atomicAdd((float*)C + (size_t)tok * NFULL + col,
                                      acc[m][n][i] + bv[n]);
                        }
                    }
                }
            }
        }
    } else {
        #pragma unroll
        for (int n = 0; n < 4; ++n) {
            int col = n_add + n0 + wn * 64 + n * 16 + lrow;
            #pragma unroll
            for (int m = 0; m < 4; ++m) {
                int rbase = m0 + wm * 64 + m * 16 + kg * 4;
                #pragma unroll
                for (int i = 0; i < 4; ++i) {
                    float v = acc[m][n][i] + bv[n];
                    if (RELU) v = fmaxf(v, 0.f);
                    ((unsigned short*)C)[((size_t)e * RP + rbase + i) * NFULL + col] = f2bf(v);
                }
            }
        }
    }
}

extern "C" void kernel_launch(void* const* d_in, const int* in_sizes, int n_in,
                              void* d_out, int out_size, void* d_ws, size_t ws_size,
                              hipStream_t stream)
{
    const float* x  = (const float*)d_in[0];
    const float* rw = (const float*)d_in[1];
    const float* rb = (const float*)d_in[2];
    const float* w1 = (const float*)d_in[3];
    const float* b1 = (const float*)d_in[4];
    const float* w2 = (const float*)d_in[5];
    const float* b2 = (const float*)d_in[6];
    float* out = (float*)d_out;

    char* ws = (char*)d_ws;
    int*   eidx    = (int*)(ws);                         // 16384 int
    int*   s2t     = (int*)(ws + 65536);                 // 2560 int
    int*   counts  = (int*)(ws + 75776);                 // 8 int
    float* sumprob = (float*)(ws + 75840);               // 8 f32
    float* part    = (float*)(ws + 98304);               // [8][16384][8] f32, 4 MB
    unsigned short* xb = (unsigned short*)(ws + 98304 + 4194304);            // 6.29 MB
    unsigned short* h  = (unsigned short*)(ws + 98304 + 4194304 + 6291456);  // 25.2 MB
    unsigned short* W  = (unsigned short*)(ws + 98304 + 4194304 + 6291456 + 25165824);

    size_t wbase = 98304 + 4194304 + 6291456 + 25165824;
    size_t avail = (ws_size > wbase) ? ws_size - wbase : 0;
    int NCH = 1;
    while (NCH < 8 && ((size_t)NE * DFF * DM * 2) / NCH > avail) NCH <<= 1;

    hipLaunchKernelGGL(k_zero_out, dim3(1024), dim3(256), 0, stream,
                       (float4*)out, T_TOK * DM / 4);
    hipLaunchKernelGGL(k_init, dim3(1), dim3(64), 0, stream, sumprob);
    hipLaunchKernelGGL(k_logits, dim3(T_TOK / 256, RSPLIT), dim3(256), 0, stream,
                       x, rw, part);
    hipLaunchKernelGGL(k_reduce, dim3(T_TOK / 256), dim3(256), 0, stream,
                       part, rb, eidx, sumprob);
    hipLaunchKernelGGL(k_scan, dim3(NE), dim3(1024), 0, stream, eidx, s2t, counts);
    hipLaunchKernelGGL(k_lb, dim3(1), dim3(64), 0, stream,
                       counts, sumprob, out + (size_t)T_TOK * DM);
    hipLaunchKernelGGL(k_gather, dim3(NE * RP), dim3(256), 0, stream, x, s2t, xb);

    // GEMM1: h = relu(xb @ w1 + b1); w1t chunks: bf16 [NE][chn1][DM]
    int chn1 = DFF / NCH;
    for (int c = 0; c < NCH; ++c) {
        hipLaunchKernelGGL((k_cvt_t<DM, DFF>), dim3(chn1 / 64, DM / 64, NE),
                           dim3(256), 0, stream, w1, W, c * chn1, chn1);
        hipLaunchKernelGGL((k_gemm<32, DM, DFF, true, false, unsigned short>),
                           dim3(8 * (chn1 / 128) * 3), dim3(256), 0, stream,
                           xb, W, b1, h, (const int*)nullptr, chn1 / 128, chn1, c * chn1);
    }

    // GEMM2: out[tok] += h @ w2 + b2 (split-K=2 atomics); w2t chunks: bf16 [NE][chn2][DFF]
    int chn2 = DM / NCH;
    for (int c = 0; c < NCH; ++c) {
        hipLaunchKernelGGL((k_cvt_t<DFF, DM>), dim3(chn2 / 64, DFF / 64, NE),
                           dim3(256), 0, stream, w2, W, c * chn2, chn2);
        hipLaunchKernelGGL((k_gemm<64, DFF, DM, false, true, float>),
                           dim3(8 * (chn2 / 128) * 3 * 2), dim3(256), 0, stream,
                           h, W, b2, out, s2t, chn2 / 128, chn2, c * chn2);
    }
}